// Round 1
// baseline (292.213 us; speedup 1.0000x reference)
//
#include <hip/hip_runtime.h>
#include <stdint.h>
#include <math.h>

#define Hh 128
#define Ww 128
#define Vn 16
#define An 8
#define Pn 64
#define Cn 3
#define HWc (Hh*Ww)
#define MAXT 50

// DIRS = [(1,0),(0,1),(-1,0),(0,-1),(1,1),(-1,1),(1,-1),(-1,-1)]  (dr, dc)
__constant__ int c_DR[8] = {1, 0, -1, 0, 1, -1, 1, -1};
__constant__ int c_DC[8] = {0, 1, 0, -1, 1, 1, -1, -1};

// ---- JAX threefry2x32 (20 rounds), bit-exact -------------------------------
__device__ __forceinline__ void tf2x32(uint32_t k0, uint32_t k1,
                                       uint32_t x0, uint32_t x1,
                                       uint32_t& o0, uint32_t& o1) {
  uint32_t ks2 = k0 ^ k1 ^ 0x1BD11BDAu;
  x0 += k0; x1 += k1;
#define TFR(r) { x0 += x1; x1 = (x1 << (r)) | (x1 >> (32 - (r))); x1 ^= x0; }
  TFR(13) TFR(15) TFR(26) TFR(6)
  x0 += k1;  x1 += ks2 + 1u;
  TFR(17) TFR(29) TFR(16) TFR(24)
  x0 += ks2; x1 += k0 + 2u;
  TFR(13) TFR(15) TFR(26) TFR(6)
  x0 += k0;  x1 += k1 + 3u;
  TFR(17) TFR(29) TFR(16) TFR(24)
  x0 += k1;  x1 += ks2 + 4u;
  TFR(13) TFR(15) TFR(26) TFR(6)
  x0 += ks2; x1 += k0 + 5u;
#undef TFR
  o0 = x0; o1 = x1;
}

// ---- init: firsts sentinel, zero counts, derive the 6 split keys -----------
__global__ void k_init(uint32_t* firsts, uint32_t* counts, uint32_t* keys) {
  int t = threadIdx.x;
  if (t < Vn) firsts[t] = 0x7FFFFFFFu;
  if (t < An) counts[t] = 0u;
  if (t == 0) {
    // jax.random.split(key(42), 6): threefry_2x32(key=(0,42), iota(12))
    // x0 = [0..5], x1 = [6..11]; out = [o0_0..o0_5, o1_0..o1_5]; keys = out.reshape(6,2)
    for (uint32_t b = 0; b < 6; ++b) {
      uint32_t o0, o1;
      tf2x32(0u, 42u, b, b + 6u, o0, o1);
      keys[b]     = o0;
      keys[6 + b] = o1;
    }
  }
}

// ---- conv3x3 SAME + bias + argmax over 16 channels + first-occurrence ------
__global__ __launch_bounds__(256) void k_conv(const float* __restrict__ obs,
                                              const float* __restrict__ cw,
                                              const float* __restrict__ cb,
                                              uint8_t* __restrict__ grid8,
                                              uint32_t* __restrict__ firsts) {
  __shared__ float sw[Vn * Cn * 9];
  __shared__ float sb[Vn];
  int t = threadIdx.x;
  for (int i = t; i < Vn * Cn * 9; i += 256) sw[i] = cw[i];
  if (t < Vn) sb[t] = cb[t];
  __syncthreads();

  int cell = blockIdx.x * 256 + t;
  int r = cell >> 7, c = cell & 127;
  float best = -INFINITY; int bi = 0;
  for (int v = 0; v < Vn; ++v) {
    float acc = 0.f;
    for (int ch = 0; ch < Cn; ++ch) {
      for (int ky = 0; ky < 3; ++ky) {
        int rr = r + ky - 1;
        if (rr < 0 || rr >= Hh) continue;
        for (int kx = 0; kx < 3; ++kx) {
          int cc = c + kx - 1;
          if (cc < 0 || cc >= Ww) continue;
          acc += obs[(ch * Hh + rr) * Ww + cc] * sw[(v * Cn + ch) * 9 + ky * 3 + kx];
        }
      }
    }
    acc += sb[v];
    if (acc > best) { best = acc; bi = v; }  // first max on tie
  }
  grid8[cell] = (uint8_t)bi;
  atomicMin(&firsts[bi], (uint32_t)cell);
}

// Gumbel-argmax categorical for ray pair (n, n+8192): threefry block j gives
// word0 -> low ray's gumbel, word1 -> high ray's gumbel (half-split = n==8192).
__device__ __forceinline__ void samp2(uint32_t k0, uint32_t k1, uint32_t jbase,
                                      int V, const float* __restrict__ wt, int p,
                                      int& s_lo, int& s_hi) {
  const uint32_t half = 524288u * (uint32_t)V;  // HW*P/2 * V
  float b_lo = -INFINITY, b_hi = -INFINITY;
  int i_lo = 0, i_hi = 0;
  for (int v = 0; v < V; ++v) {
    uint32_t o0, o1;
    tf2x32(k0, k1, jbase + (uint32_t)v, jbase + (uint32_t)v + half, o0, o1);
    float f0 = __uint_as_float((o0 >> 9) | 0x3f800000u) - 1.0f;
    float f1 = __uint_as_float((o1 >> 9) | 0x3f800000u) - 1.0f;
    if (f0 == 0.0f) f0 = 1.17549435e-38f;  // max(tiny, u)
    if (f1 == 0.0f) f1 = 1.17549435e-38f;
    float w = wt[v * Pn + p];
    float a0 = w - logf(-logf(f0));  // w + gumbel
    float a1 = w - logf(-logf(f1));
    if (a0 > b_lo) { b_lo = a0; i_lo = v; }
    if (a1 > b_hi) { b_hi = a1; i_hi = v; }
  }
  s_lo = i_lo; s_hi = i_hi;
}

__device__ __forceinline__ int do_cond(const uint8_t* __restrict__ g8,
                                       const int* __restrict__ s_fr,
                                       const int* __restrict__ s_fc,
                                       const int* __restrict__ s_ex,
                                       int so, int sp, int sn, int sd, int sx) {
  int cond = 0;
  if (s_ex[so]) {
    int r = s_fr[so], c = s_fc[so];
    int dr = c_DR[sd], dc = c_DC[sd];
    for (int t = 0; t < MAXT; ++t) {
      r += dr; c += dc;
      if ((unsigned)r >= (unsigned)Hh || (unsigned)c >= (unsigned)Ww) { cond = 0; break; }
      int val = g8[(r << 7) + c];
      if (val == sp) { cond = 1; break; }  // hit_pos wins ties with hit_neg
      if (val == sn) { cond = 0; break; }
    }
  }
  return cond ^ sx;  // is_not flip
}

__global__ __launch_bounds__(256) void k_rays(const uint8_t* __restrict__ grid8g,
                                              const uint32_t* __restrict__ firsts,
                                              const float* __restrict__ w_obj,
                                              const float* __restrict__ w_pos,
                                              const float* __restrict__ w_neg,
                                              const float* __restrict__ w_act,
                                              const float* __restrict__ w_dir,
                                              const float* __restrict__ w_not,
                                              const uint32_t* __restrict__ keys,
                                              uint32_t* __restrict__ counts) {
  __shared__ uint8_t g8[HWc];
  __shared__ float t_obj[Vn * Pn], t_pos[Vn * Pn], t_neg[Vn * Pn];
  __shared__ float t_act[An * Pn], t_dir[8 * Pn], t_not[2 * Pn];
  __shared__ int s_fr[Vn], s_fc[Vn], s_ex[Vn];
  __shared__ uint32_t cnt[An];
  __shared__ uint32_t sk[12];

  int t = threadIdx.x;
  // stage grid (16 KB) into LDS
  {
    const uint32_t* g32 = (const uint32_t*)grid8g;
    uint32_t* s32 = (uint32_t*)g8;
    for (int i = t; i < HWc / 4; i += 256) s32[i] = g32[i];
  }
  // transpose weights to [v][p] so lane==p reads are conflict-free
  for (int i = t; i < Vn * Pn; i += 256) {
    int p = i >> 4, v = i & 15;
    t_obj[v * Pn + p] = w_obj[i];
    t_pos[v * Pn + p] = w_pos[i];
    t_neg[v * Pn + p] = w_neg[i];
  }
  for (int i = t; i < An * Pn; i += 256) {
    int p = i >> 3, a = i & 7;
    t_act[a * Pn + p] = w_act[i];
    t_dir[a * Pn + p] = w_dir[i];
  }
  for (int i = t; i < 2 * Pn; i += 256) {
    int p = i >> 1, a = i & 1;
    t_not[a * Pn + p] = w_not[i];
  }
  if (t < Vn) {
    uint32_t f = firsts[t];
    int ex = f < (uint32_t)HWc;
    s_ex[t] = ex;
    s_fr[t] = ex ? (int)(f >> 7) : 0;
    s_fc[t] = ex ? (int)(f & 127u) : 0;
  }
  if (t < An) cnt[t] = 0u;
  if (t < 12) sk[t] = keys[t];
  __syncthreads();

  int gid = blockIdx.x * 256 + t;        // 0 .. 524287
  int p = gid & 63;
  uint32_t base = (uint32_t)gid;          // == nlo*64 + p, nlo in [0,8192)

  int so_lo, so_hi, sp_lo, sp_hi, sn_lo, sn_hi, sa_lo, sa_hi, sd_lo, sd_hi, sx_lo, sx_hi;
  samp2(sk[0],  sk[1],  base * 16u, 16, t_obj, p, so_lo, so_hi);
  samp2(sk[2],  sk[3],  base * 16u, 16, t_pos, p, sp_lo, sp_hi);
  samp2(sk[4],  sk[5],  base * 16u, 16, t_neg, p, sn_lo, sn_hi);
  samp2(sk[6],  sk[7],  base * 8u,   8, t_act, p, sa_lo, sa_hi);
  samp2(sk[8],  sk[9],  base * 8u,   8, t_dir, p, sd_lo, sd_hi);
  samp2(sk[10], sk[11], base * 2u,   2, t_not, p, sx_lo, sx_hi);

  int c_lo = do_cond(g8, s_fr, s_fc, s_ex, so_lo, sp_lo, sn_lo, sd_lo, sx_lo);
  int c_hi = do_cond(g8, s_fr, s_fc, s_ex, so_hi, sp_hi, sn_hi, sd_hi, sx_hi);

  if (c_lo) atomicAdd(&cnt[sa_lo], 1u);
  if (c_hi) atomicAdd(&cnt[sa_hi], 1u);
  __syncthreads();
  if (t < An && cnt[t]) atomicAdd(&counts[t], cnt[t]);
}

__global__ void k_softmax(const uint32_t* __restrict__ counts, float* __restrict__ out) {
  int t = threadIdx.x;
  if (t < An) {
    float m = -INFINITY;
    float c[An];
    for (int i = 0; i < An; ++i) { c[i] = (float)counts[i]; m = fmaxf(m, c[i]); }
    float s = 0.f;
    for (int i = 0; i < An; ++i) s += expf(c[i] - m);
    out[t] = expf(c[t] - m) / s;
  }
}

extern "C" void kernel_launch(void* const* d_in, const int* in_sizes, int n_in,
                              void* d_out, int out_size, void* d_ws, size_t ws_size,
                              hipStream_t stream) {
  const float* obs    = (const float*)d_in[0];
  const float* conv_w = (const float*)d_in[1];
  const float* conv_b = (const float*)d_in[2];
  const float* w_obj  = (const float*)d_in[3];
  const float* w_pos  = (const float*)d_in[4];
  const float* w_neg  = (const float*)d_in[5];
  const float* w_act  = (const float*)d_in[6];
  const float* w_dir  = (const float*)d_in[7];
  const float* w_not  = (const float*)d_in[8];
  float* out = (float*)d_out;

  uint8_t* ws = (uint8_t*)d_ws;
  uint32_t* firsts = (uint32_t*)(ws + 0);    // 16 * 4 = 64 B
  uint32_t* counts = (uint32_t*)(ws + 64);   // 8 * 4  = 32 B
  uint32_t* keys   = (uint32_t*)(ws + 96);   // 12 * 4 = 48 B
  uint8_t*  grid8  = ws + 160;               // 16384 B

  k_init<<<dim3(1), dim3(64), 0, stream>>>(firsts, counts, keys);
  k_conv<<<dim3(HWc / 256), dim3(256), 0, stream>>>(obs, conv_w, conv_b, grid8, firsts);
  k_rays<<<dim3(2048), dim3(256), 0, stream>>>(grid8, firsts, w_obj, w_pos, w_neg,
                                               w_act, w_dir, w_not, keys, counts);
  k_softmax<<<dim3(1), dim3(64), 0, stream>>>(counts, out);
}

// Round 2
// 263.012 us; speedup vs baseline: 1.1110x; 1.1110x over previous
//
#include <hip/hip_runtime.h>
#include <stdint.h>
#include <math.h>

#define Hh 128
#define Ww 128
#define Vn 16
#define An 8
#define Pn 64
#define Cn 3
#define HWc (Hh*Ww)
#define MAXT 50

// DIRS = [(1,0),(0,1),(-1,0),(0,-1),(1,1),(-1,1),(1,-1),(-1,-1)]  (dr, dc)
__constant__ int c_DR[8] = {1, 0, -1, 0, 1, -1, 1, -1};
__constant__ int c_DC[8] = {0, 1, 0, -1, 1, 1, -1, -1};

// ---- JAX threefry2x32 (20 rounds), bit-exact -------------------------------
__device__ __forceinline__ void tf2x32(uint32_t k0, uint32_t k1,
                                       uint32_t x0, uint32_t x1,
                                       uint32_t& o0, uint32_t& o1) {
  uint32_t ks2 = k0 ^ k1 ^ 0x1BD11BDAu;
  x0 += k0; x1 += k1;
#define TFR(r) { x0 += x1; x1 = __builtin_rotateleft32(x1, (r)); x1 ^= x0; }
  TFR(13) TFR(15) TFR(26) TFR(6)
  x0 += k1;  x1 += ks2 + 1u;
  TFR(17) TFR(29) TFR(16) TFR(24)
  x0 += ks2; x1 += k0 + 2u;
  TFR(13) TFR(15) TFR(26) TFR(6)
  x0 += k0;  x1 += k1 + 3u;
  TFR(17) TFR(29) TFR(16) TFR(24)
  x0 += k1;  x1 += ks2 + 4u;
  TFR(13) TFR(15) TFR(26) TFR(6)
  x0 += ks2; x1 += k0 + 5u;
#undef TFR
  o0 = x0; o1 = x1;
}

// ---- init: firsts sentinel, zero counts, derive the 6 split keys -----------
__global__ void k_init(uint32_t* firsts, uint32_t* counts, uint32_t* keys) {
  int t = threadIdx.x;
  if (t < Vn) firsts[t] = 0x7FFFFFFFu;
  if (t < An) counts[t] = 0u;
  if (t == 0) {
    // jax.random.split(key(42), 6): threefry_2x32(key=(0,42), iota(12))
    for (uint32_t b = 0; b < 6; ++b) {
      uint32_t o0, o1;
      tf2x32(0u, 42u, b, b + 6u, o0, o1);
      keys[b]     = o0;
      keys[6 + b] = o1;
    }
  }
}

// ---- conv3x3 SAME + bias + argmax over 16 channels + first-occurrence ------
__global__ __launch_bounds__(256) void k_conv(const float* __restrict__ obs,
                                              const float* __restrict__ cw,
                                              const float* __restrict__ cb,
                                              uint8_t* __restrict__ grid8,
                                              uint32_t* __restrict__ firsts) {
  __shared__ float sw[Vn * Cn * 9];
  __shared__ float sb[Vn];
  int t = threadIdx.x;
  for (int i = t; i < Vn * Cn * 9; i += 256) sw[i] = cw[i];
  if (t < Vn) sb[t] = cb[t];
  __syncthreads();

  int cell = blockIdx.x * 256 + t;
  int r = cell >> 7, c = cell & 127;
  float best = -INFINITY; int bi = 0;
  for (int v = 0; v < Vn; ++v) {
    float acc = 0.f;
    for (int ch = 0; ch < Cn; ++ch) {
      for (int ky = 0; ky < 3; ++ky) {
        int rr = r + ky - 1;
        if (rr < 0 || rr >= Hh) continue;
        for (int kx = 0; kx < 3; ++kx) {
          int cc = c + kx - 1;
          if (cc < 0 || cc >= Ww) continue;
          acc += obs[(ch * Hh + rr) * Ww + cc] * sw[(v * Cn + ch) * 9 + ky * 3 + kx];
        }
      }
    }
    acc += sb[v];
    if (acc > best) { best = acc; bi = v; }  // first max on tie
  }
  grid8[cell] = (uint8_t)bi;
  atomicMin(&firsts[bi], (uint32_t)cell);
}

// ---- precompute cond for all (so, sd, sp, sn) combos -> packed bit table ---
// idx = (((so<<3)|sd)<<8) | (sp<<4) | sn ; 32768 bits = 1024 uint32 words.
__global__ __launch_bounds__(256) void k_pre(const uint8_t* __restrict__ grid8g,
                                             const uint32_t* __restrict__ firsts,
                                             uint32_t* __restrict__ table) {
  __shared__ uint8_t g8[HWc];
  __shared__ int s_fr[Vn], s_fc[Vn], s_ex[Vn];
  int t = threadIdx.x;
  {
    const uint4* g = (const uint4*)grid8g;
    uint4* s = (uint4*)g8;
    for (int i = t; i < HWc / 16; i += 256) s[i] = g[i];
  }
  if (t < Vn) {
    uint32_t f = firsts[t];
    int ex = f < (uint32_t)HWc;
    s_ex[t] = ex;
    s_fr[t] = ex ? (int)(f >> 7) : 0;
    s_fc[t] = ex ? (int)(f & 127u) : 0;
  }
  __syncthreads();

  int gid = blockIdx.x * 256 + t;   // 0 .. 32767
  int sn = gid & 15, sp = (gid >> 4) & 15, sd = (gid >> 8) & 7, so = gid >> 11;
  int cond = 0;
  if (s_ex[so]) {
    int r = s_fr[so], c = s_fc[so];
    int dr = c_DR[sd], dc = c_DC[sd];
    for (int i = 0; i < MAXT; ++i) {
      r += dr; c += dc;
      if ((unsigned)r >= (unsigned)Hh || (unsigned)c >= (unsigned)Ww) { cond = 0; break; }
      int val = g8[(r << 7) + c];
      if (val == sp) { cond = 1; break; }  // hit_pos wins ties with hit_neg
      if (val == sn) { cond = 0; break; }
    }
  }
  unsigned long long m = __ballot(cond);
  int lane = t & 63;
  if (lane == 0)       table[gid >> 5] = (uint32_t)m;
  else if (lane == 32) table[gid >> 5] = (uint32_t)(m >> 32);
}

// Gumbel-argmax categorical for ray pair (n, n+524288): threefry block j gives
// word0 -> low ray, word1 -> high ray (JAX half-split of the iota).
// Score uses: -log(-log u) = -ln2*log2(-log2 u) + const, const cancels in argmax.
template <int V>
__device__ __forceinline__ void samp2(uint32_t k0, uint32_t k1, uint32_t jbase,
                                      const float* __restrict__ wt, int p,
                                      int& s_lo, int& s_hi) {
  const uint32_t half = 524288u * (uint32_t)V;  // HW*P/2 * V
  float b_lo = -INFINITY, b_hi = -INFINITY;
  int i_lo = 0, i_hi = 0;
#pragma unroll 2
  for (int v = 0; v < V; ++v) {
    uint32_t o0, o1;
    tf2x32(k0, k1, jbase + (uint32_t)v, jbase + (uint32_t)v + half, o0, o1);
    float w = wt[v * Pn + p];
    float u0 = fmaxf(__uint_as_float((o0 >> 9) | 0x3f800000u) - 1.0f, 1.17549435e-38f);
    float u1 = fmaxf(__uint_as_float((o1 >> 9) | 0x3f800000u) - 1.0f, 1.17549435e-38f);
    float a0 = fmaf(__log2f(-__log2f(u0)), -0.69314718056f, w);
    float a1 = fmaf(__log2f(-__log2f(u1)), -0.69314718056f, w);
    if (a0 > b_lo) { b_lo = a0; i_lo = v; }  // first max on tie
    if (a1 > b_hi) { b_hi = a1; i_hi = v; }
  }
  s_lo = i_lo; s_hi = i_hi;
}

__global__ __launch_bounds__(256) void k_rays(const float* __restrict__ w_obj,
                                              const float* __restrict__ w_pos,
                                              const float* __restrict__ w_neg,
                                              const float* __restrict__ w_act,
                                              const float* __restrict__ w_dir,
                                              const float* __restrict__ w_not,
                                              const uint32_t* __restrict__ keys,
                                              const uint32_t* __restrict__ table,
                                              uint32_t* __restrict__ counts) {
  __shared__ float t_obj[Vn * Pn], t_pos[Vn * Pn], t_neg[Vn * Pn];
  __shared__ float t_act[An * Pn], t_dir[8 * Pn], t_not[2 * Pn];
  __shared__ uint32_t sTab[1024];
  __shared__ uint32_t cnt[An];
  __shared__ uint32_t sk[12];

  int t = threadIdx.x;
  // transpose weights to [v][p] so lane==p reads are 2-way (free) in LDS
  for (int i = t; i < Vn * Pn; i += 256) {
    int p = i >> 4, v = i & 15;
    t_obj[v * Pn + p] = w_obj[i];
    t_pos[v * Pn + p] = w_pos[i];
    t_neg[v * Pn + p] = w_neg[i];
  }
  for (int i = t; i < An * Pn; i += 256) {
    int p = i >> 3, a = i & 7;
    t_act[a * Pn + p] = w_act[i];
    t_dir[a * Pn + p] = w_dir[i];
  }
  for (int i = t; i < 2 * Pn; i += 256) {
    int p = i >> 1, a = i & 1;
    t_not[a * Pn + p] = w_not[i];
  }
  for (int i = t; i < 1024; i += 256) sTab[i] = table[i];
  if (t < An) cnt[t] = 0u;
  if (t < 12) sk[t] = keys[t];
  __syncthreads();

  int gid = blockIdx.x * 256 + t;        // 0 .. 524287
  int p = gid & 63;
  uint32_t base = (uint32_t)gid;

  int so_lo, so_hi, sp_lo, sp_hi, sn_lo, sn_hi, sa_lo, sa_hi, sd_lo, sd_hi, sx_lo, sx_hi;
  samp2<16>(sk[0],  sk[1],  base * 16u, t_obj, p, so_lo, so_hi);
  samp2<16>(sk[2],  sk[3],  base * 16u, t_pos, p, sp_lo, sp_hi);
  samp2<16>(sk[4],  sk[5],  base * 16u, t_neg, p, sn_lo, sn_hi);
  samp2<8>( sk[6],  sk[7],  base * 8u,  t_act, p, sa_lo, sa_hi);
  samp2<8>( sk[8],  sk[9],  base * 8u,  t_dir, p, sd_lo, sd_hi);
  samp2<2>( sk[10], sk[11], base * 2u,  t_not, p, sx_lo, sx_hi);

  int idx_lo = (((so_lo << 3) | sd_lo) << 8) | (sp_lo << 4) | sn_lo;
  int idx_hi = (((so_hi << 3) | sd_hi) << 8) | (sp_hi << 4) | sn_hi;
  int c_lo = ((sTab[idx_lo >> 5] >> (idx_lo & 31)) & 1u) ^ sx_lo;
  int c_hi = ((sTab[idx_hi >> 5] >> (idx_hi & 31)) & 1u) ^ sx_hi;

  if (c_lo) atomicAdd(&cnt[sa_lo], 1u);
  if (c_hi) atomicAdd(&cnt[sa_hi], 1u);
  __syncthreads();
  if (t < An && cnt[t]) atomicAdd(&counts[t], cnt[t]);
}

__global__ void k_softmax(const uint32_t* __restrict__ counts, float* __restrict__ out) {
  int t = threadIdx.x;
  if (t < An) {
    float m = -INFINITY;
    float c[An];
    for (int i = 0; i < An; ++i) { c[i] = (float)counts[i]; m = fmaxf(m, c[i]); }
    float s = 0.f;
    for (int i = 0; i < An; ++i) s += expf(c[i] - m);
    out[t] = expf(c[t] - m) / s;
  }
}

extern "C" void kernel_launch(void* const* d_in, const int* in_sizes, int n_in,
                              void* d_out, int out_size, void* d_ws, size_t ws_size,
                              hipStream_t stream) {
  const float* obs    = (const float*)d_in[0];
  const float* conv_w = (const float*)d_in[1];
  const float* conv_b = (const float*)d_in[2];
  const float* w_obj  = (const float*)d_in[3];
  const float* w_pos  = (const float*)d_in[4];
  const float* w_neg  = (const float*)d_in[5];
  const float* w_act  = (const float*)d_in[6];
  const float* w_dir  = (const float*)d_in[7];
  const float* w_not  = (const float*)d_in[8];
  float* out = (float*)d_out;

  uint8_t* ws = (uint8_t*)d_ws;
  uint32_t* firsts = (uint32_t*)(ws + 0);     // 16 * 4
  uint32_t* counts = (uint32_t*)(ws + 64);    // 8 * 4
  uint32_t* keys   = (uint32_t*)(ws + 96);    // 12 * 4
  uint8_t*  grid8  = ws + 256;                // 16384 B
  uint32_t* table  = (uint32_t*)(ws + 256 + 16384);  // 4096 B

  k_init<<<dim3(1), dim3(64), 0, stream>>>(firsts, counts, keys);
  k_conv<<<dim3(HWc / 256), dim3(256), 0, stream>>>(obs, conv_w, conv_b, grid8, firsts);
  k_pre<<<dim3(128), dim3(256), 0, stream>>>(grid8, firsts, table);
  k_rays<<<dim3(2048), dim3(256), 0, stream>>>(w_obj, w_pos, w_neg,
                                               w_act, w_dir, w_not, keys, table, counts);
  k_softmax<<<dim3(1), dim3(64), 0, stream>>>(counts, out);
}